// Round 10
// baseline (1166.986 us; speedup 1.0000x reference)
//
#include <hip/hip_runtime.h>

#define N_NODES 500000
#define N_EDGES 5000000
#define D 16

#define FSH 7                               // fine bucket: 128 nodes
#define FBN (1 << FSH)
#define NFINE ((N_NODES + FBN - 1) >> FSH)  // 3907
#define NFPAD 4096
#define CSH 13                              // coarse bucket: 8192 nodes
#define NC 64                               // coarse buckets (62 used)
#define AP 17                               // padded LDS agg stride
#define CHUNK 2048
#define BIN_CHUNK 8192
#define NBIN_BLOCKS ((N_EDGES + BIN_CHUNK - 1) / BIN_CHUNK)  // 611

// ---------------------------------------------------------------------------
// 1) Histogram of fine dst-buckets (dst >> 7).
// ---------------------------------------------------------------------------
__global__ __launch_bounds__(256) void hist_kernel(
    const int* __restrict__ edge_index, int* __restrict__ cnt) {
    __shared__ int h[NFINE];
    for (int i = threadIdx.x; i < NFINE; i += 256) h[i] = 0;
    __syncthreads();
    int stride = gridDim.x * 256;
    for (int e = blockIdx.x * 256 + threadIdx.x; e < N_EDGES; e += stride)
        atomicAdd(&h[edge_index[N_EDGES + e] >> FSH], 1);
    __syncthreads();
    for (int i = threadIdx.x; i < NFINE; i += 256)
        if (h[i]) atomicAdd(&cnt[i], h[i]);
}

// ---------------------------------------------------------------------------
// 2) Exclusive scan over NFPAD fine counts (single block, 16/thread).
// ---------------------------------------------------------------------------
__global__ __launch_bounds__(256) void scan_kernel(
    const int* __restrict__ cnt, int* __restrict__ base, int* __restrict__ cursorf) {
    __shared__ int sums[256];
    int t = threadIdx.x;
    int v[16]; int ts = 0;
    #pragma unroll
    for (int j = 0; j < 16; ++j) {
        int i = t * 16 + j;
        v[j] = (i < NFINE) ? cnt[i] : 0;
        ts += v[j];
    }
    sums[t] = ts;
    __syncthreads();
    for (int off = 1; off < 256; off <<= 1) {
        int val = (t >= off) ? sums[t - off] : 0;
        __syncthreads();
        if (t >= off) sums[t] += val;
        __syncthreads();
    }
    int p = sums[t] - ts;
    #pragma unroll
    for (int j = 0; j < 16; ++j) {
        int i = t * 16 + j;
        base[i] = p; cursorf[i] = p;
        p += v[j];
    }
    if (t == 255) base[NFPAD] = p;   // = N_EDGES
}

// ---------------------------------------------------------------------------
// 2b) Coarse cursors: cursorc[c] = base[c*64].
// ---------------------------------------------------------------------------
__global__ void initc_kernel(const int* __restrict__ base, int* __restrict__ cursorc) {
    int c = threadIdx.x;
    if (c < NC) cursorc[c] = base[c << 6];
}

// ---------------------------------------------------------------------------
// 3) Pass 1: bin edges by coarse dst-bucket (dst>>13), coalesced ~520B runs.
//    Entry e1 = (src << 13) | (dst & 8191).
// ---------------------------------------------------------------------------
__global__ __launch_bounds__(256) void binc_kernel(
    const int* __restrict__ edge_index, int* __restrict__ cursorc,
    unsigned int* __restrict__ out1) {
    __shared__ unsigned int buf[BIN_CHUNK];      // 32 KB
    __shared__ unsigned char bkey[BIN_CHUNK];    // 8 KB
    __shared__ int hist[NC], lofs[NC], gofs[NC];
    int t = threadIdx.x;
    int start = blockIdx.x * BIN_CHUNK;
    int count = min(BIN_CHUNK, N_EDGES - start);

    if (t < NC) hist[t] = 0;
    __syncthreads();
    for (int k = t; k < count; k += 256)
        atomicAdd(&hist[edge_index[N_EDGES + start + k] >> CSH], 1);
    __syncthreads();
    if (t == 0) { int p = 0; for (int i = 0; i < NC; ++i) { lofs[i] = p; p += hist[i]; } }
    __syncthreads();
    if (t < NC) {
        int c = hist[t];
        gofs[t] = c ? atomicAdd(&cursorc[t], c) : 0;
        hist[t] = lofs[t];                       // reuse as local cursor
    }
    __syncthreads();
    for (int k = t; k < count; k += 256) {
        int s = edge_index[start + k];
        int d = edge_index[N_EDGES + start + k];
        int c = d >> CSH;
        int pos = atomicAdd(&hist[c], 1);
        buf[pos] = ((unsigned int)s << CSH) | (unsigned int)(d & ((1 << CSH) - 1));
        bkey[pos] = (unsigned char)c;
    }
    __syncthreads();
    for (int i = t; i < count; i += 256) {
        int c = bkey[i];
        out1[gofs[c] + (i - lofs[c])] = buf[i];
    }
}

// ---------------------------------------------------------------------------
// 4) Pass 2: within each coarse bucket, bin by fine bucket (64 sub-bins),
//    coalesced ~320B runs. e2 = (src << 7) | (dst & 127).
// ---------------------------------------------------------------------------
__global__ __launch_bounds__(256) void binf_kernel(
    const unsigned int* __restrict__ in1, const int* __restrict__ base,
    int* __restrict__ cursorf, unsigned int* __restrict__ out2) {
    __shared__ unsigned int buf[BIN_CHUNK];
    __shared__ unsigned char bkey[BIN_CHUNK];
    __shared__ int hist[NC], lofs[NC], gofs[NC];
    int t = threadIdx.x;
    int c = blockIdx.x >> 4, b = blockIdx.x & 15;
    int cs = base[c << 6], ce = base[(c + 1) << 6];
    int cnt = ce - cs;
    if (cnt <= 0) return;
    int chunk = (cnt + 15) >> 4;
    int s0 = cs + b * chunk;
    int s1 = min(s0 + chunk, ce);

    for (int sub = s0; sub < s1; sub += BIN_CHUNK) {
        int count = min(BIN_CHUNK, s1 - sub);
        if (t < NC) hist[t] = 0;
        __syncthreads();
        for (int k = t; k < count; k += 256)
            atomicAdd(&hist[(in1[sub + k] >> FSH) & 63], 1);
        __syncthreads();
        if (t == 0) { int p = 0; for (int i = 0; i < NC; ++i) { lofs[i] = p; p += hist[i]; } }
        __syncthreads();
        if (t < NC) {
            int cc = hist[t];
            gofs[t] = cc ? atomicAdd(&cursorf[(c << 6) + t], cc) : 0;
            hist[t] = lofs[t];
        }
        __syncthreads();
        for (int k = t; k < count; k += 256) {
            unsigned int e1 = in1[sub + k];
            int f = (e1 >> FSH) & 63;
            int pos = atomicAdd(&hist[f], 1);
            buf[pos] = ((e1 >> CSH) << FSH) | (e1 & (FBN - 1));
            bkey[pos] = (unsigned char)f;
        }
        __syncthreads();
        for (int i = t; i < count; i += 256) {
            int f = bkey[i];
            out2[gofs[f] + (i - lofs[f])] = buf[i];
        }
        __syncthreads();
    }
}

// ---------------------------------------------------------------------------
// 5) Fused layer 1: block owns 128-node fine bucket; batched-8 independent
//    gathers -> LDS f32 accumulate; cooperative (16 lanes/node) transform.
// ---------------------------------------------------------------------------
__global__ __launch_bounds__(256, 6) void layer1_kernel(
    const float* __restrict__ x,
    const unsigned int* __restrict__ bin2, const int* __restrict__ base,
    const float* __restrict__ w_rel, const float* __restrict__ b_rel,
    const float* __restrict__ w_root,
    float* __restrict__ h1) {
    __shared__ float agg[FBN * AP];              // 8.7 KB
    __shared__ float sWrelT[256], sWrootT[256], sB[16];
    __shared__ unsigned int sE[CHUNK];           // 8 KB
    int t = threadIdx.x;
    {
        int r = t >> 4, cc = t & 15;
        sWrelT[cc * 16 + r] = w_rel[r * 16 + cc];
        sWrootT[cc * 16 + r] = w_root[r * 16 + cc];
        if (t < 16) sB[t] = b_rel[t];
    }
    for (int i = t; i < FBN * AP; i += 256) agg[i] = 0.f;
    __syncthreads();

    int bkt = blockIdx.x;
    int e0 = base[bkt], e1 = base[bkt + 1];
    int g = t >> 4, j = t & 15;

    for (int c0 = e0; c0 < e1; c0 += CHUNK) {
        int m = min(CHUNK, e1 - c0);
        for (int i = t; i < m; i += 256) sE[i] = bin2[c0 + i];
        __syncthreads();
        int i = g;
        for (; i + 7 * 16 < m; i += 8 * 16) {
            unsigned int u[8]; float vv[8];
            #pragma unroll
            for (int k = 0; k < 8; ++k) u[k] = sE[i + k * 16];
            #pragma unroll
            for (int k = 0; k < 8; ++k) vv[k] = x[(long)(u[k] >> FSH) * D + j];
            #pragma unroll
            for (int k = 0; k < 8; ++k)
                atomicAdd(&agg[(u[k] & (FBN - 1)) * AP + j], vv[k]);
        }
        for (; i < m; i += 16) {
            unsigned int u = sE[i];
            atomicAdd(&agg[(u & (FBN - 1)) * AP + j], x[(long)(u >> FSH) * D + j]);
        }
        __syncthreads();
    }

    // cooperative node transform: 16 lanes per node, lane j = output dim
    int lane = t & 63;
    for (int n = g; n < FBN; n += 16) {
        int node = (bkt << FSH) + n;
        if (node >= N_NODES) continue;           // group-uniform
        float v = x[(long)node * D + j];
        float acc = sB[j];
        #pragma unroll
        for (int k = 0; k < 16; ++k) {
            float xk = __shfl(v, (lane & 48) | k, 64);
            acc += agg[n * AP + k] * sWrelT[k * 16 + j] + xk * sWrootT[k * 16 + j];
        }
        h1[(long)node * D + j] = acc > 0.f ? acc : 0.f;
    }
}

// ---------------------------------------------------------------------------
// 6) Fused layer 2 + head.
// ---------------------------------------------------------------------------
__global__ __launch_bounds__(256, 6) void layer2_kernel(
    const float* __restrict__ h1,
    const unsigned int* __restrict__ bin2, const int* __restrict__ base,
    const float* __restrict__ w_rel, const float* __restrict__ b_rel,
    const float* __restrict__ w_root,
    const float* __restrict__ fc1_w, const float* __restrict__ fc1_b,
    const float* __restrict__ fc2_w, const float* __restrict__ fc2_b,
    float* __restrict__ out) {
    __shared__ float agg[FBN * AP];
    __shared__ float sWrelT[256], sWrootT[256], sB[16];
    __shared__ float sF1w[8 * D], sF1b[8], sF2w[2 * 8], sF2b[2];
    __shared__ unsigned int sE[CHUNK];
    int t = threadIdx.x;
    {
        int r = t >> 4, cc = t & 15;
        sWrelT[cc * 16 + r] = w_rel[r * 16 + cc];
        sWrootT[cc * 16 + r] = w_root[r * 16 + cc];
        if (t < 16) sB[t] = b_rel[t];
        if (t < 8 * D) sF1w[t] = fc1_w[t];
        if (t < 8) sF1b[t] = fc1_b[t];
        if (t < 16) sF2w[t] = fc2_w[t];
        if (t < 2) sF2b[t] = fc2_b[t];
    }
    for (int i = t; i < FBN * AP; i += 256) agg[i] = 0.f;
    __syncthreads();

    int bkt = blockIdx.x;
    int e0 = base[bkt], e1 = base[bkt + 1];
    int g = t >> 4, j = t & 15;

    for (int c0 = e0; c0 < e1; c0 += CHUNK) {
        int m = min(CHUNK, e1 - c0);
        for (int i = t; i < m; i += 256) sE[i] = bin2[c0 + i];
        __syncthreads();
        int i = g;
        for (; i + 7 * 16 < m; i += 8 * 16) {
            unsigned int u[8]; float vv[8];
            #pragma unroll
            for (int k = 0; k < 8; ++k) u[k] = sE[i + k * 16];
            #pragma unroll
            for (int k = 0; k < 8; ++k) vv[k] = h1[(long)(u[k] >> FSH) * D + j];
            #pragma unroll
            for (int k = 0; k < 8; ++k)
                atomicAdd(&agg[(u[k] & (FBN - 1)) * AP + j], vv[k]);
        }
        for (; i < m; i += 16) {
            unsigned int u = sE[i];
            atomicAdd(&agg[(u & (FBN - 1)) * AP + j], h1[(long)(u >> FSH) * D + j]);
        }
        __syncthreads();
    }

    // h2 = relu(conv2) cooperatively, stored back into agg rows
    int lane = t & 63;
    for (int n = g; n < FBN; n += 16) {
        int node = (bkt << FSH) + n;
        if (node >= N_NODES) continue;
        float v = h1[(long)node * D + j];
        float acc = sB[j];
        #pragma unroll
        for (int k = 0; k < 16; ++k) {
            float xk = __shfl(v, (lane & 48) | k, 64);
            acc += agg[n * AP + k] * sWrelT[k * 16 + j] + xk * sWrootT[k * 16 + j];
        }
        agg[n * AP + j] = acc > 0.f ? acc : 0.f;   // reads above precede write
    }
    __syncthreads();

    // head: one thread per node
    if (t < FBN) {
        int node = (bkt << FSH) + t;
        if (node < N_NODES) {
            float h3[8];
            #pragma unroll
            for (int jj = 0; jj < 8; ++jj) {
                float acc = sF1b[jj];
                #pragma unroll
                for (int k = 0; k < 16; ++k) acc += agg[t * AP + k] * sF1w[jj * 16 + k];
                h3[jj] = acc > 0.f ? acc : 0.f;
            }
            float o0 = sF2b[0], o1 = sF2b[1];
            #pragma unroll
            for (int jj = 0; jj < 8; ++jj) {
                o0 += h3[jj] * sF2w[jj];
                o1 += h3[jj] * sF2w[8 + jj];
            }
            ((float2*)out)[node] = make_float2(o0, o1);
        }
    }
}

extern "C" void kernel_launch(void* const* d_in, const int* in_sizes, int n_in,
                              void* d_out, int out_size, void* d_ws, size_t ws_size,
                              hipStream_t stream) {
    const float* x          = (const float*)d_in[0];
    const int*   edge_index = (const int*)d_in[1];
    const float* c1_wrel    = (const float*)d_in[2];
    const float* c1_brel    = (const float*)d_in[3];
    const float* c1_wroot   = (const float*)d_in[4];
    const float* c2_wrel    = (const float*)d_in[5];
    const float* c2_brel    = (const float*)d_in[6];
    const float* c2_wroot   = (const float*)d_in[7];
    const float* fc1_w      = (const float*)d_in[8];
    const float* fc1_b      = (const float*)d_in[9];
    const float* fc2_w      = (const float*)d_in[10];
    const float* fc2_b      = (const float*)d_in[11];
    float* out = (float*)d_out;

    // Workspace: bin1 20MB | bin2 20MB | h1 32MB | cnt/base/cursors ~48KB
    unsigned int* bin1 = (unsigned int*)d_ws;
    unsigned int* bin2 = bin1 + N_EDGES;
    float* h1    = (float*)(bin2 + N_EDGES);
    int* cnt     = (int*)(h1 + (size_t)N_NODES * D);
    int* base    = cnt + NFPAD;
    int* cursorf = base + NFPAD + 1;
    int* cursorc = cursorf + NFPAD;

    // --- Two-level dst binning (amortized over both layers) ---
    hipMemsetAsync(cnt, 0, NFPAD * sizeof(int), stream);
    hist_kernel<<<1024, 256, 0, stream>>>(edge_index, cnt);
    scan_kernel<<<1, 256, 0, stream>>>(cnt, base, cursorf);
    initc_kernel<<<1, 64, 0, stream>>>(base, cursorc);
    binc_kernel<<<NBIN_BLOCKS, 256, 0, stream>>>(edge_index, cursorc, bin1);
    binf_kernel<<<NC * 16, 256, 0, stream>>>(bin1, base, cursorf, bin2);

    // --- Fused layers (no global atomics) ---
    layer1_kernel<<<NFINE, 256, 0, stream>>>(
        x, bin2, base, c1_wrel, c1_brel, c1_wroot, h1);
    layer2_kernel<<<NFINE, 256, 0, stream>>>(
        h1, bin2, base, c2_wrel, c2_brel, c2_wroot,
        fc1_w, fc1_b, fc2_w, fc2_b, out);
}

// Round 11
// 649.262 us; speedup vs baseline: 1.7974x; 1.7974x over previous
//
#include <hip/hip_runtime.h>
#include <hip/hip_fp16.h>

#define N_NODES 500000
#define N_EDGES 5000000
#define D 16

// ---------------------------------------------------------------------------
// Scatter layer 1: agg1[dst][p] += half2(x[src][2p..2p+1])
// tid = e*8 + p. 8 lanes/edge: coalesced 64B float2 gather of x[src],
// one packed-f16 atomic dword per lane, fire-and-forget.
// Measured (R4/R6): ~247-249 us, bound by global atomic RMW throughput
// (~160 G pk-dword/s); gather fetch rides along free (R6: 296->17.7 MB
// fetch change, same duration).
// ---------------------------------------------------------------------------
__global__ __launch_bounds__(256) void scatter1_kernel(
    const float* __restrict__ x,
    const int* __restrict__ edge_index,   // [2, E]
    __half2* __restrict__ agg) {          // [N][8]
    long tid = (long)blockIdx.x * 256 + threadIdx.x;
    if (tid >= (long)N_EDGES * 8) return;
    int e = (int)(tid >> 3);
    int p = (int)(tid & 7);
    int s = edge_index[e];
    int t = edge_index[N_EDGES + e];
    float2 v = ((const float2*)(x + (long)s * D))[p];
    unsafeAtomicAdd(&agg[(long)t * 8 + p], __float22half2_rn(v));
}

// ---------------------------------------------------------------------------
// Scatter layer 2: agg2[dst][p] += half2(h1[src][2p..2p+1])  (h1 in f32)
// ---------------------------------------------------------------------------
__global__ __launch_bounds__(256) void scatter2_kernel(
    const float* __restrict__ h1,         // [N][16] f32
    const int* __restrict__ edge_index,
    __half2* __restrict__ agg) {
    long tid = (long)blockIdx.x * 256 + threadIdx.x;
    if (tid >= (long)N_EDGES * 8) return;
    int e = (int)(tid >> 3);
    int p = (int)(tid & 7);
    int s = edge_index[e];
    int t = edge_index[N_EDGES + e];
    float2 v = ((const float2*)(h1 + (long)s * D))[p];
    unsafeAtomicAdd(&agg[(long)t * 8 + p], __float22half2_rn(v));
}

// ---------------------------------------------------------------------------
// Node layer 1: h1[i] = relu(agg1[i] @ Wrel^T + b + x[i] @ Wroot^T), f32 out.
// ---------------------------------------------------------------------------
__global__ __launch_bounds__(256) void node1_kernel(
    const float* __restrict__ x,
    const __half2* __restrict__ agg,
    const float* __restrict__ w_rel,   // [D][D]
    const float* __restrict__ b_rel,
    const float* __restrict__ w_root,
    float* __restrict__ h1) {
    __shared__ float sWrel[D * D];
    __shared__ float sWroot[D * D];
    __shared__ float sB[D];
    for (int i = threadIdx.x; i < D * D; i += blockDim.x) {
        sWrel[i] = w_rel[i];
        sWroot[i] = w_root[i];
    }
    if (threadIdx.x < D) sB[threadIdx.x] = b_rel[threadIdx.x];
    __syncthreads();

    int i = blockIdx.x * blockDim.x + threadIdx.x;
    if (i >= N_NODES) return;

    float a[D], xi[D];
    {
        __half2 hrow[8];
        const float4* ap = (const float4*)(agg + (long)i * 8);
        *(float4*)&hrow[0] = ap[0];
        *(float4*)&hrow[4] = ap[1];
        #pragma unroll
        for (int q = 0; q < 8; ++q) {
            float2 f = __half22float2(hrow[q]);
            a[2 * q] = f.x; a[2 * q + 1] = f.y;
        }
        const float4* xp = (const float4*)(x + (long)i * D);
        #pragma unroll
        for (int q = 0; q < 4; ++q) {
            float4 xv = xp[q];
            xi[q * 4 + 0] = xv.x; xi[q * 4 + 1] = xv.y;
            xi[q * 4 + 2] = xv.z; xi[q * 4 + 3] = xv.w;
        }
    }

    float4* hp = (float4*)(h1 + (long)i * D);
    #pragma unroll
    for (int q = 0; q < 4; ++q) {
        float4 o;
        float* op = &o.x;
        #pragma unroll
        for (int r = 0; r < 4; ++r) {
            int dd = q * 4 + r;
            float acc = sB[dd];
            #pragma unroll
            for (int k = 0; k < D; ++k)
                acc += a[k] * sWrel[dd * D + k] + xi[k] * sWroot[dd * D + k];
            op[r] = acc > 0.f ? acc : 0.f;
        }
        hp[q] = o;
    }
}

// ---------------------------------------------------------------------------
// Node layer 2 + head: h2 = relu(agg2 @ W2rel^T + b2 + h1 @ W2root^T)
//                      out = relu(h2 @ fc1^T + b1) @ fc2^T + b2
// ---------------------------------------------------------------------------
__global__ __launch_bounds__(256) void node2_kernel(
    const float* __restrict__ h1,
    const __half2* __restrict__ agg,
    const float* __restrict__ w_rel,
    const float* __restrict__ b_rel,
    const float* __restrict__ w_root,
    const float* __restrict__ fc1_w,  // [8][16]
    const float* __restrict__ fc1_b,
    const float* __restrict__ fc2_w,  // [2][8]
    const float* __restrict__ fc2_b,
    float* __restrict__ out) {
    __shared__ float sWrel[D * D];
    __shared__ float sWroot[D * D];
    __shared__ float sB[D];
    __shared__ float sF1w[8 * D];
    __shared__ float sF1b[8];
    __shared__ float sF2w[2 * 8];
    __shared__ float sF2b[2];
    for (int i = threadIdx.x; i < D * D; i += blockDim.x) {
        sWrel[i] = w_rel[i];
        sWroot[i] = w_root[i];
    }
    if (threadIdx.x < D) sB[threadIdx.x] = b_rel[threadIdx.x];
    if (threadIdx.x < 8 * D) sF1w[threadIdx.x] = fc1_w[threadIdx.x];
    if (threadIdx.x < 8) sF1b[threadIdx.x] = fc1_b[threadIdx.x];
    if (threadIdx.x < 16) sF2w[threadIdx.x] = fc2_w[threadIdx.x];
    if (threadIdx.x < 2) sF2b[threadIdx.x] = fc2_b[threadIdx.x];
    __syncthreads();

    int i = blockIdx.x * blockDim.x + threadIdx.x;
    if (i >= N_NODES) return;

    float a[D], xi[D];
    {
        __half2 hrow[8];
        const float4* ap = (const float4*)(agg + (long)i * 8);
        *(float4*)&hrow[0] = ap[0];
        *(float4*)&hrow[4] = ap[1];
        #pragma unroll
        for (int q = 0; q < 8; ++q) {
            float2 f = __half22float2(hrow[q]);
            a[2 * q] = f.x; a[2 * q + 1] = f.y;
        }
        const float4* xp = (const float4*)(h1 + (long)i * D);
        #pragma unroll
        for (int q = 0; q < 4; ++q) {
            float4 xv = xp[q];
            xi[q * 4 + 0] = xv.x; xi[q * 4 + 1] = xv.y;
            xi[q * 4 + 2] = xv.z; xi[q * 4 + 3] = xv.w;
        }
    }

    float h2[D];
    #pragma unroll
    for (int dd = 0; dd < D; ++dd) {
        float acc = sB[dd];
        #pragma unroll
        for (int k = 0; k < D; ++k)
            acc += a[k] * sWrel[dd * D + k] + xi[k] * sWroot[dd * D + k];
        h2[dd] = acc > 0.f ? acc : 0.f;
    }

    float h3[8];
    #pragma unroll
    for (int j = 0; j < 8; ++j) {
        float acc = sF1b[j];
        #pragma unroll
        for (int k = 0; k < D; ++k) acc += h2[k] * sF1w[j * D + k];
        h3[j] = acc > 0.f ? acc : 0.f;
    }

    float2 o;
    {
        float acc0 = sF2b[0], acc1 = sF2b[1];
        #pragma unroll
        for (int j = 0; j < 8; ++j) {
            acc0 += h3[j] * sF2w[0 * 8 + j];
            acc1 += h3[j] * sF2w[1 * 8 + j];
        }
        o.x = acc0;
        o.y = acc1;
    }
    ((float2*)out)[i] = o;
}

extern "C" void kernel_launch(void* const* d_in, const int* in_sizes, int n_in,
                              void* d_out, int out_size, void* d_ws, size_t ws_size,
                              hipStream_t stream) {
    const float* x          = (const float*)d_in[0];
    const int*   edge_index = (const int*)d_in[1];
    const float* c1_wrel    = (const float*)d_in[2];
    const float* c1_brel    = (const float*)d_in[3];
    const float* c1_wroot   = (const float*)d_in[4];
    const float* c2_wrel    = (const float*)d_in[5];
    const float* c2_brel    = (const float*)d_in[6];
    const float* c2_wroot   = (const float*)d_in[7];
    const float* fc1_w      = (const float*)d_in[8];
    const float* fc1_b      = (const float*)d_in[9];
    const float* fc2_w      = (const float*)d_in[10];
    const float* fc2_b      = (const float*)d_in[11];
    float* out = (float*)d_out;

    // Workspace: agg1 16MB | agg2 16MB (adjacent -> single memset) | h1 f32 32MB
    __half2* agg1 = (__half2*)d_ws;
    __half2* agg2 = agg1 + (size_t)N_NODES * 8;
    float*   h1   = (float*)(agg2 + (size_t)N_NODES * 8);

    const int BLK = 256;
    long scatter_total = (long)N_EDGES * 8;
    int scatter_blocks = (int)((scatter_total + BLK - 1) / BLK);
    int node_blocks = (N_NODES + BLK - 1) / BLK;

    // One memset zeroes both agg buffers (32 MB)
    hipMemsetAsync(agg1, 0, 2 * (size_t)N_NODES * 8 * sizeof(__half2), stream);

    // Layer 1
    scatter1_kernel<<<scatter_blocks, BLK, 0, stream>>>(x, edge_index, agg1);
    node1_kernel<<<node_blocks, BLK, 0, stream>>>(x, agg1, c1_wrel, c1_brel, c1_wroot, h1);

    // Layer 2 + head
    scatter2_kernel<<<scatter_blocks, BLK, 0, stream>>>(h1, edge_index, agg2);
    node2_kernel<<<node_blocks, BLK, 0, stream>>>(h1, agg2, c2_wrel, c2_brel, c2_wroot,
                                                  fc1_w, fc1_b, fc2_w, fc2_b, out);
}